// Round 16
// baseline (698.597 us; speedup 1.0000x reference)
//
#include <hip/hip_runtime.h>
#include <cstdint>

#define NU 100000
#define NI 100000
#define NN 200000
#define NE 3200000
#define TXT 768
#define NBF 640        // blocks for non-ranged count/fill passes

typedef _Float16 f16x8 __attribute__((ext_vector_type(8)));
typedef _Float16 f16x4 __attribute__((ext_vector_type(4)));
typedef float    f32x4 __attribute__((ext_vector_type(4)));

typedef __attribute__((address_space(1))) const unsigned int guint;
typedef __attribute__((address_space(3))) unsigned int luint;

__device__ __forceinline__ float lrelu(float x) { return x >= 0.f ? x : 0.01f * x; }

#define MEMFENCE asm volatile("" ::: "memory")
#define WAIT_VM(N)  asm volatile("s_waitcnt vmcnt(" #N ")" ::: "memory")
#define WAIT_LGKM0  asm volatile("s_waitcnt lgkmcnt(0)" ::: "memory")
#define BARRIER     do { __builtin_amdgcn_s_barrier(); MEMFENCE; } while (0)

// ---------------------------------------------------------------------------
// prep: [0,640) count (single pass) | [640,3765) copy_emb | [3765,3957) pack_w1
// ---------------------------------------------------------------------------
__global__ __launch_bounds__(256) void prep_kernel(
    const int* __restrict__ erow,
    const float* __restrict__ uemb, const float* __restrict__ iemb,
    const float* __restrict__ ueW1, const float* __restrict__ ieW1,
    int* __restrict__ cnt,
    _Float16* __restrict__ ego16, float* __restrict__ outp,
    _Float16* __restrict__ w1p)
{
    const int b = blockIdx.x;
    const int tid = threadIdx.x;

    if (b < NBF) {
        const int4* e4 = (const int4*)erow;
        for (int c = b * 256 + tid; c < NE / 4; c += NBF * 256) {
            int4 v = e4[c];
            atomicAdd(&cnt[v.x], 1);
            atomicAdd(&cnt[v.y], 1);
            atomicAdd(&cnt[v.z], 1);
            atomicAdd(&cnt[v.w], 1);
        }
    } else if (b < NBF + 3125) {
        int idx = (b - NBF) * 256 + tid;
        if (idx >= NN * 4) return;
        int n = idx >> 2, q = idx & 3;
        float4 v;
        if (n < NU) v = ((const float4*)uemb)[(size_t)n * 4 + q];
        else        v = ((const float4*)iemb)[(size_t)(n - NU) * 4 + q];
        f16x4 h;
        h[0] = (_Float16)v.x; h[1] = (_Float16)v.y;
        h[2] = (_Float16)v.z; h[3] = (_Float16)v.w;
        *(f16x4*)(ego16 + (size_t)n * 32 + q * 4) = h;
        ((float4*)outp)[(size_t)n * 32 + q] = v;
    } else {
        int i = (b - (NBF + 3125)) * 256 + tid;  // 0..49151
        int side = (i >= 24576);
        int ii = i - side * 24576;
        const float* W1 = side ? ieW1 : ueW1;
        int j   = ii & 7;
        int ln  = (ii >> 3) & 63;
        int kbH = ii >> 9;
        int kb  = kbH >> 1, H = kbH & 1;
        int k   = kb * 32 + (ln >> 4) * 8 + j;
        int c   = H * 16 + (ln & 15);
        w1p[i] = (_Float16)W1[k * 32 + c];
    }
}

// ---------------------------------------------------------------------------
// scan / offsets
// ---------------------------------------------------------------------------
__global__ __launch_bounds__(256) void scan_blk_kernel(const int* __restrict__ cnt,
                                                       int* __restrict__ rp,
                                                       int* __restrict__ bsum)
{
    __shared__ int ts[256];
    const int tid = threadIdx.x;
    const int base = blockIdx.x * 1024 + tid * 4;
    int v0 = (base + 0 < NN) ? cnt[base + 0] : 0;
    int v1 = (base + 1 < NN) ? cnt[base + 1] : 0;
    int v2 = (base + 2 < NN) ? cnt[base + 2] : 0;
    int v3 = (base + 3 < NN) ? cnt[base + 3] : 0;
    int s = v0 + v1 + v2 + v3;
    ts[tid] = s;
    __syncthreads();
    for (int off = 1; off < 256; off <<= 1) {
        int t = (tid >= off) ? ts[tid - off] : 0;
        __syncthreads();
        ts[tid] += t;
        __syncthreads();
    }
    int excl = ts[tid] - s;
    if (base + 0 < NN) rp[base + 0] = excl;
    if (base + 1 < NN) rp[base + 1] = excl + v0;
    if (base + 2 < NN) rp[base + 2] = excl + v0 + v1;
    if (base + 3 < NN) rp[base + 3] = excl + v0 + v1 + v2;
    if (tid == 255) bsum[blockIdx.x] = ts[255];
}

__global__ __launch_bounds__(256) void scan_bsum_kernel(int* __restrict__ bsum, int nblk)
{
    __shared__ int ts[256];
    const int tid = threadIdx.x;
    int v = (tid < nblk) ? bsum[tid] : 0;
    ts[tid] = v;
    __syncthreads();
    for (int off = 1; off < 256; off <<= 1) {
        int t = (tid >= off) ? ts[tid - off] : 0;
        __syncthreads();
        ts[tid] += t;
        __syncthreads();
    }
    if (tid < nblk) bsum[tid] = ts[tid] - v;
}

__global__ __launch_bounds__(256) void add_off_kernel(int* __restrict__ rp,
                                                      const int* __restrict__ bsum,
                                                      int* __restrict__ cur)
{
    int i = blockIdx.x * 256 + threadIdx.x;
    if (i < NN) {
        int v = rp[i] + bsum[i >> 10];
        rp[i] = v;
        cur[i] = v;
    }
    if (i == 0) rp[NN] = NE;
}

// ---------------------------------------------------------------------------
// Merged fill + MLP. Blocks [0,NBF) = single-pass CSR fill (dispatched FIRST
// so they co-run under the MLP instead of trailing it); blocks [NBF,NBF+1024)
// = MFMA MLP (v4 body unchanged). rec.x = col | ((row&63)<<18)
// ---------------------------------------------------------------------------
__global__ __launch_bounds__(256, 4) void mlp_fill_kernel(
    const float* __restrict__ Xu, const float* __restrict__ Xi,
    const _Float16* __restrict__ w1pack,
    const float* __restrict__ ueW2, const float* __restrict__ ieW2,
    _Float16* __restrict__ ego16,
    float* __restrict__ outp,
    const int* __restrict__ erow, const int* __restrict__ ecol,
    const float* __restrict__ eval,
    int* __restrict__ cur, uint2* __restrict__ recs)
{
    __shared__ float buf[2][4096];
    __shared__ float part[3][512];
    __shared__ _Float16 hbuf[640];

    const int tid = threadIdx.x;

    if (blockIdx.x < NBF) {
        // ---------------- fill path (single pass, runs first) ----------------
        const int b = blockIdx.x;
        const int4*   e4 = (const int4*)erow;
        const int4*   c4 = (const int4*)ecol;
        const float4* f4 = (const float4*)eval;
        for (int c = b * 256 + tid; c < NE / 4; c += NBF * 256) {
            int4 v   = e4[c];
            int4 cc  = c4[c];
            float4 vv = f4[c];
            int p0 = atomicAdd(&cur[v.x], 1);
            recs[p0] = make_uint2((unsigned)cc.x | ((unsigned)(v.x & 63) << 18),
                                  __float_as_uint(vv.x));
            int p1 = atomicAdd(&cur[v.y], 1);
            recs[p1] = make_uint2((unsigned)cc.y | ((unsigned)(v.y & 63) << 18),
                                  __float_as_uint(vv.y));
            int p2 = atomicAdd(&cur[v.z], 1);
            recs[p2] = make_uint2((unsigned)cc.z | ((unsigned)(v.z & 63) << 18),
                                  __float_as_uint(vv.z));
            int p3 = atomicAdd(&cur[v.w], 1);
            recs[p3] = make_uint2((unsigned)cc.w | ((unsigned)(v.w & 63) << 18),
                                  __float_as_uint(vv.w));
        }
        return;
    }

    // ---------------- mlp path (v4 body) ----------------
    const int bj    = blockIdx.x - NBF;   // 0..1023
    const int lane  = tid & 63;
    const int wv    = tid >> 6;
    const int row16 = lane & 15;
    const int cg    = lane >> 4;
    const int rx7   = row16 & 7;

    f16x8 bw2u, bw2i;
    #pragma unroll
    for (int j = 0; j < 8; ++j) {
        bw2u[j] = (_Float16)ueW2[((lane >> 4) * 8 + j) * 16 + (lane & 15)];
        bw2i[j] = (_Float16)ieW2[((lane >> 4) * 8 + j) * 16 + (lane & 15)];
    }

    const int tA = (int)(((long)bj * 12500) >> 10);
    const int tB = (int)(((long)(bj + 1) * 12500) >> 10);

    for (int t = tA; t < tB; ++t) {
        const bool isU = t < 6250;
        const int tile = isU ? t : t - 6250;
        const float* xt = (isU ? Xu : Xi) + (size_t)tile * 16 * TXT;
        const _Float16* w1p = w1pack + (isU ? 0 : 24576);

#define STAGE(bb, cc) do {                                                      \
            _Pragma("unroll")                                                   \
            for (int i_ = 0; i_ < 4; ++i_) {                                    \
                const int r_ = wv * 4 + i_;                                     \
                const float* g_ = xt + (size_t)r_ * TXT + (cc) * 256            \
                                  + ((lane ^ (r_ & 7)) << 2);                   \
                __builtin_amdgcn_global_load_lds((guint*)g_,                    \
                    (luint*)&buf[bb][r_ * 256], 16, 0, 0);                      \
            }                                                                   \
        } while (0)

#define MCHUNK(bb, cc) do {                                                     \
            _Pragma("unroll")                                                   \
            for (int kl2 = 0; kl2 < 2; ++kl2) {                                 \
                const int kbl = wv * 2 + kl2;                                   \
                const int kb  = (cc) * 8 + kbl;                                 \
                f16x8 b0 = *(const f16x8*)&w1p[(kb * 2 + 0) * 512 + lane * 8];  \
                f16x8 b1 = *(const f16x8*)&w1p[(kb * 2 + 1) * 512 + lane * 8];  \
                const int u0 = kbl * 8 + cg * 2;                                \
                f32x4 xa = *(const f32x4*)&buf[bb][row16 * 256 + ((u0 ^ rx7) << 2)]; \
                f32x4 xb = *(const f32x4*)&buf[bb][row16 * 256 + (((u0 + 1) ^ rx7) << 2)]; \
                f16x8 a;                                                        \
                a[0] = (_Float16)xa[0]; a[1] = (_Float16)xa[1];                 \
                a[2] = (_Float16)xa[2]; a[3] = (_Float16)xa[3];                 \
                a[4] = (_Float16)xb[0]; a[5] = (_Float16)xb[1];                 \
                a[6] = (_Float16)xb[2]; a[7] = (_Float16)xb[3];                 \
                c0 = __builtin_amdgcn_mfma_f32_16x16x32_f16(a, b0, c0, 0, 0, 0); \
                c1 = __builtin_amdgcn_mfma_f32_16x16x32_f16(a, b1, c1, 0, 0, 0); \
            }                                                                   \
        } while (0)

        f32x4 c0 = {0.f, 0.f, 0.f, 0.f};
        f32x4 c1 = {0.f, 0.f, 0.f, 0.f};

        STAGE(0, 0);
        STAGE(1, 1);
        WAIT_VM(4);
        BARRIER;
        MCHUNK(0, 0);
        WAIT_LGKM0;
        BARRIER;
        STAGE(0, 2);
        WAIT_VM(4);
        BARRIER;
        MCHUNK(1, 1);
        WAIT_LGKM0;
        WAIT_VM(0);
        BARRIER;
        MCHUNK(0, 2);
        WAIT_LGKM0;

        if (wv > 0) {
            *(f32x4*)&part[wv - 1][lane * 8]     = c0;
            *(f32x4*)&part[wv - 1][lane * 8 + 4] = c1;
            WAIT_LGKM0;
        }
        BARRIER;

        if (wv == 0) {
            #pragma unroll
            for (int p = 0; p < 3; ++p) {
                f32x4 pa = *(const f32x4*)&part[p][lane * 8];
                f32x4 pb = *(const f32x4*)&part[p][lane * 8 + 4];
                c0 += pa; c1 += pb;
            }
            #pragma unroll
            for (int j = 0; j < 4; ++j) {
                int r = cg * 4 + j;
                hbuf[r * 40 + row16]      = (_Float16)fmaxf(c0[j], 0.f);
                hbuf[r * 40 + row16 + 16] = (_Float16)fmaxf(c1[j], 0.f);
            }
            const _Float16* ap = &hbuf[row16 * 40 + cg * 8];
            f16x4 lo = *(const f16x4*)ap;
            f16x4 hi = *(const f16x4*)(ap + 4);
            f16x8 a2;
            a2[0] = lo[0]; a2[1] = lo[1]; a2[2] = lo[2]; a2[3] = lo[3];
            a2[4] = hi[0]; a2[5] = hi[1]; a2[6] = hi[2]; a2[7] = hi[3];

            f32x4 c2 = {0.f, 0.f, 0.f, 0.f};
            f16x8 bw2 = isU ? bw2u : bw2i;
            c2 = __builtin_amdgcn_mfma_f32_16x16x32_f16(a2, bw2, c2, 0, 0, 0);

            const int rbase = (isU ? 0 : NU) + tile * 16 + cg * 4;
            #pragma unroll
            for (int j = 0; j < 4; ++j) {
                float v = c2[j];
                ego16[(size_t)(rbase + j) * 32  + 16 + row16] = (_Float16)v;
                outp [(size_t)(rbase + j) * 128 + 16 + row16] = v;
            }
        }
#undef STAGE
#undef MCHUNK
    }
}

// ---------------------------------------------------------------------------
// Pull+update v5: v2 structure, but recs loads are LANE-DISTRIBUTED within
// each 8-lane slot group (lane q loads recs[e+q]) and broadcast via shfl —
// VMEM issue per (rec,lane) drops from 2 to 1.125 (VALU has headroom).
// Gather / run-accumulation / LDS-atomic flush identical to v2.
// ---------------------------------------------------------------------------
__global__ __launch_bounds__(256) void pull_update_v5(
    const int* __restrict__ rp, const uint2* __restrict__ recs,
    const _Float16* __restrict__ egoIn, _Float16* __restrict__ egoOut,
    float* __restrict__ outp,
    const float* __restrict__ gcW, const float* __restrict__ gcb,
    const float* __restrict__ biW, const float* __restrict__ bib, int l)
{
    __shared__ float acc[64][33];
    __shared__ float Wg[32][36];
    __shared__ float Wb[32][36];
    __shared__ float bgs[32], bbs[32];

    const int tid = threadIdx.x;
    for (int i = tid; i < 64 * 33; i += 256) ((float*)acc)[i] = 0.f;
    for (int i = tid; i < 1024; i += 256) {
        Wg[i >> 5][i & 31] = gcW[l * 1024 + i];
        Wb[i >> 5][i & 31] = biW[l * 1024 + i];
    }
    if (tid < 32) { bgs[tid] = gcb[l * 32 + tid]; bbs[tid] = bib[l * 32 + tid]; }

    const int r0 = blockIdx.x * 64;
    const int eBeg = rp[r0], eEnd = rp[r0 + 64];
    __syncthreads();

    const int cnt  = eEnd - eBeg;
    const int s    = tid >> 3;       // slot 0..31
    const int q    = tid & 7;        // dim quad 0..7
    const int lane = tid & 63;
    const int gb   = lane & 56;      // slot-group base lane within wave
    const int L    = (cnt + 31) >> 5;
    const int e0   = eBeg + s * L;
    const int e1   = min(e0 + L, eEnd);

    float4 a4 = make_float4(0.f, 0.f, 0.f, 0.f);
    int curRl = -1;

    auto PROC = [&](unsigned rx, unsigned ry, f16x4 vv) {
        int rl = (int)(rx >> 18);
        float a = __uint_as_float(ry);
        if (rl != curRl) {
            if (curRl >= 0) {
                atomicAdd(&acc[curRl][q * 4 + 0], a4.x);
                atomicAdd(&acc[curRl][q * 4 + 1], a4.y);
                atomicAdd(&acc[curRl][q * 4 + 2], a4.z);
                atomicAdd(&acc[curRl][q * 4 + 3], a4.w);
            }
            a4 = make_float4(0.f, 0.f, 0.f, 0.f);
            curRl = rl;
        }
        a4.x += a * (float)vv[0];
        a4.y += a * (float)vv[1];
        a4.z += a * (float)vv[2];
        a4.w += a * (float)vv[3];
    };

    int e = e0;
    for (; e + 8 <= e1; e += 8) {
        uint2 my = recs[e + q];   // each lane loads ONE rec of the group's 8
        unsigned x0 = (unsigned)__shfl((int)my.x, gb | 0, 64);
        unsigned y0 = (unsigned)__shfl((int)my.y, gb | 0, 64);
        unsigned x1 = (unsigned)__shfl((int)my.x, gb | 1, 64);
        unsigned y1 = (unsigned)__shfl((int)my.y, gb | 1, 64);
        unsigned x2 = (unsigned)__shfl((int)my.x, gb | 2, 64);
        unsigned y2 = (unsigned)__shfl((int)my.y, gb | 2, 64);
        unsigned x3 = (unsigned)__shfl((int)my.x, gb | 3, 64);
        unsigned y3 = (unsigned)__shfl((int)my.y, gb | 3, 64);
        unsigned x4 = (unsigned)__shfl((int)my.x, gb | 4, 64);
        unsigned y4 = (unsigned)__shfl((int)my.y, gb | 4, 64);
        unsigned x5 = (unsigned)__shfl((int)my.x, gb | 5, 64);
        unsigned y5 = (unsigned)__shfl((int)my.y, gb | 5, 64);
        unsigned x6 = (unsigned)__shfl((int)my.x, gb | 6, 64);
        unsigned y6 = (unsigned)__shfl((int)my.y, gb | 6, 64);
        unsigned x7 = (unsigned)__shfl((int)my.x, gb | 7, 64);
        unsigned y7 = (unsigned)__shfl((int)my.y, gb | 7, 64);
        f16x4 v0 = *(const f16x4*)(egoIn + (size_t)(x0 & 0x3FFFF) * 32 + q * 4);
        f16x4 v1 = *(const f16x4*)(egoIn + (size_t)(x1 & 0x3FFFF) * 32 + q * 4);
        f16x4 v2 = *(const f16x4*)(egoIn + (size_t)(x2 & 0x3FFFF) * 32 + q * 4);
        f16x4 v3 = *(const f16x4*)(egoIn + (size_t)(x3 & 0x3FFFF) * 32 + q * 4);
        f16x4 v4 = *(const f16x4*)(egoIn + (size_t)(x4 & 0x3FFFF) * 32 + q * 4);
        f16x4 v5 = *(const f16x4*)(egoIn + (size_t)(x5 & 0x3FFFF) * 32 + q * 4);
        f16x4 v6 = *(const f16x4*)(egoIn + (size_t)(x6 & 0x3FFFF) * 32 + q * 4);
        f16x4 v7 = *(const f16x4*)(egoIn + (size_t)(x7 & 0x3FFFF) * 32 + q * 4);
        PROC(x0, y0, v0); PROC(x1, y1, v1); PROC(x2, y2, v2); PROC(x3, y3, v3);
        PROC(x4, y4, v4); PROC(x5, y5, v5); PROC(x6, y6, v6); PROC(x7, y7, v7);
    }
    for (; e < e1; ++e) {
        uint2 rr = recs[e];
        f16x4 vv = *(const f16x4*)(egoIn + (size_t)(rr.x & 0x3FFFF) * 32 + q * 4);
        PROC(rr.x, rr.y, vv);
    }
    if (curRl >= 0) {
        atomicAdd(&acc[curRl][q * 4 + 0], a4.x);
        atomicAdd(&acc[curRl][q * 4 + 1], a4.y);
        atomicAdd(&acc[curRl][q * 4 + 2], a4.z);
        atomicAdd(&acc[curRl][q * 4 + 3], a4.w);
    }
    __syncthreads();

    // ---- update phase: 4 threads per row, 8 output dims each ----
    const int r    = tid >> 2;
    const int c    = tid & 3;
    const int node = r0 + r;
    const int j0   = c * 8;

    const _Float16* er = egoIn + (size_t)node * 32;
    f16x8 ev0 = *(const f16x8*)er;
    f16x8 ev1 = *(const f16x8*)(er + 8);
    f16x8 ev2 = *(const f16x8*)(er + 16);
    f16x8 ev3 = *(const f16x8*)(er + 24);

    float A[8], B[8];
    #pragma unroll
    for (int jj = 0; jj < 8; ++jj) { A[jj] = bgs[j0 + jj]; B[jj] = bbs[j0 + jj]; }

    #pragma unroll
    for (int kq = 0; kq < 4; ++kq) {
        #pragma unroll
        for (int kk = 0; kk < 8; ++kk) {
            const int k = kq * 8 + kk;
            float sk = acc[r][k];
            float evk = (kq == 0) ? (float)ev0[kk] : (kq == 1) ? (float)ev1[kk]
                      : (kq == 2) ? (float)ev2[kk] : (float)ev3[kk];
            float ek = sk * evk;
            f32x4 g0 = *(const f32x4*)&Wg[k][j0];
            f32x4 g1 = *(const f32x4*)&Wg[k][j0 + 4];
            f32x4 b0 = *(const f32x4*)&Wb[k][j0];
            f32x4 b1 = *(const f32x4*)&Wb[k][j0 + 4];
            A[0] += sk * g0[0]; A[1] += sk * g0[1]; A[2] += sk * g0[2]; A[3] += sk * g0[3];
            A[4] += sk * g1[0]; A[5] += sk * g1[1]; A[6] += sk * g1[2]; A[7] += sk * g1[3];
            B[0] += ek * b0[0]; B[1] += ek * b0[1]; B[2] += ek * b0[2]; B[3] += ek * b0[3];
            B[4] += ek * b1[0]; B[5] += ek * b1[1]; B[6] += ek * b1[2]; B[7] += ek * b1[3];
        }
    }

    float v[8];
    float ss = 0.f;
    #pragma unroll
    for (int jj = 0; jj < 8; ++jj) {
        float x = lrelu(A[jj]) + lrelu(B[jj]);
        v[jj] = x;
        ss += x * x;
    }
    ss += __shfl_xor(ss, 1, 64);
    ss += __shfl_xor(ss, 2, 64);
    float inv = 1.0f / fmaxf(sqrtf(ss), 1e-12f);

    f16x8 h;
    #pragma unroll
    for (int jj = 0; jj < 8; ++jj) h[jj] = (_Float16)v[jj];
    *(f16x8*)(egoOut + (size_t)node * 32 + j0) = h;

    float* op = outp + (size_t)node * 128 + (size_t)(l + 1) * 32 + j0;
    float4 o0 = make_float4(v[0] * inv, v[1] * inv, v[2] * inv, v[3] * inv);
    float4 o1 = make_float4(v[4] * inv, v[5] * inv, v[6] * inv, v[7] * inv);
    *(float4*)op       = o0;
    *(float4*)(op + 4) = o1;
}

// ---------------------------------------------------------------------------
extern "C" void kernel_launch(void* const* d_in, const int* in_sizes, int n_in,
                              void* d_out, int out_size, void* d_ws, size_t ws_size,
                              hipStream_t stream)
{
    const int*   erow = (const int*)d_in[0];
    const int*   ecol = (const int*)d_in[1];
    const float* evalp = (const float*)d_in[2];
    const float* une  = (const float*)d_in[3];
    const float* se   = (const float*)d_in[4];
    const float* uemb = (const float*)d_in[5];
    const float* iemb = (const float*)d_in[6];
    const float* ueW1 = (const float*)d_in[7];
    const float* ueW2 = (const float*)d_in[8];
    const float* ieW1 = (const float*)d_in[9];
    const float* ieW2 = (const float*)d_in[10];
    const float* gcW  = (const float*)d_in[11];
    const float* gcb  = (const float*)d_in[12];
    const float* biW  = (const float*)d_in[13];
    const float* bib  = (const float*)d_in[14];
    float* outp = (float*)d_out;

    _Float16* egoA16 = (_Float16*)d_ws;                 // NN*32 f16 = 12.8 MB
    _Float16* egoB16 = egoA16 + (size_t)NN * 32;        // 12.8 MB
    uint2* recs = (uint2*)(egoB16 + (size_t)NN * 32);   // NE uint2 = 25.6 MB
    int*   cnt  = (int*)(recs + (size_t)NE);            // NN
    int*   rp   = cnt + NN;                             // NN+1
    int*   cur  = rp + NN + 1;                          // NN
    int*   bsum = cur + NN;                             // 256
    _Float16* w1pack = (_Float16*)(bsum + 256);         // 2*24576 f16 = 96 KB

    const size_t need = (size_t)((char*)(w1pack + 49152) - (char*)d_ws);
    if (ws_size < need) return;

    hipMemsetAsync(cnt, 0, (size_t)NN * sizeof(int), stream);
    prep_kernel<<<NBF + 3125 + 192, 256, 0, stream>>>(erow, uemb, iemb, ueW1, ieW1,
                                                      cnt, egoA16, outp, w1pack);

    const int NBLK = (NN + 1023) / 1024;  // 196
    scan_blk_kernel<<<NBLK, 256, 0, stream>>>(cnt, rp, bsum);
    scan_bsum_kernel<<<1, 256, 0, stream>>>(bsum, NBLK);
    add_off_kernel<<<(NN + 255) / 256, 256, 0, stream>>>(rp, bsum, cur);

    // fill blocks dispatched FIRST so they co-run under the MLP.
    mlp_fill_kernel<<<NBF + 1024, 256, 0, stream>>>(
        une, se, w1pack, ueW2, ieW2, egoA16, outp,
        erow, ecol, evalp, cur, recs);

    const _Float16* egoIn = egoA16;
    _Float16* egoOut = egoB16;
    for (int l = 0; l < 3; ++l) {
        pull_update_v5<<<NN / 64, 256, 0, stream>>>(rp, recs, egoIn, egoOut, outp,
                                                    gcW, gcb, biW, bib, l);
        const _Float16* t = egoOut; egoOut = (_Float16*)egoIn; egoIn = t;
    }
}

// Round 17
// 666.987 us; speedup vs baseline: 1.0474x; 1.0474x over previous
//
#include <hip/hip_runtime.h>
#include <cstdint>

#define NU 100000
#define NI 100000
#define NN 200000
#define NE 3200000
#define TXT 768
#define NBF 640        // blocks for non-ranged count/fill passes

typedef _Float16 f16x8 __attribute__((ext_vector_type(8)));
typedef _Float16 f16x4 __attribute__((ext_vector_type(4)));
typedef float    f32x4 __attribute__((ext_vector_type(4)));

typedef __attribute__((address_space(1))) const unsigned int guint;
typedef __attribute__((address_space(3))) unsigned int luint;

__device__ __forceinline__ float lrelu(float x) { return x >= 0.f ? x : 0.01f * x; }

#define MEMFENCE asm volatile("" ::: "memory")
#define WAIT_VM(N)  asm volatile("s_waitcnt vmcnt(" #N ")" ::: "memory")
#define WAIT_LGKM0  asm volatile("s_waitcnt lgkmcnt(0)" ::: "memory")
#define BARRIER     do { __builtin_amdgcn_s_barrier(); MEMFENCE; } while (0)

// ---------------------------------------------------------------------------
// prep: [0,640) count (single pass) | [640,3765) copy_emb | [3765,3957) pack_w1
// ---------------------------------------------------------------------------
__global__ __launch_bounds__(256) void prep_kernel(
    const int* __restrict__ erow,
    const float* __restrict__ uemb, const float* __restrict__ iemb,
    const float* __restrict__ ueW1, const float* __restrict__ ieW1,
    int* __restrict__ cnt,
    _Float16* __restrict__ ego16, float* __restrict__ outp,
    _Float16* __restrict__ w1p)
{
    const int b = blockIdx.x;
    const int tid = threadIdx.x;

    if (b < NBF) {
        const int4* e4 = (const int4*)erow;
        for (int c = b * 256 + tid; c < NE / 4; c += NBF * 256) {
            int4 v = e4[c];
            atomicAdd(&cnt[v.x], 1);
            atomicAdd(&cnt[v.y], 1);
            atomicAdd(&cnt[v.z], 1);
            atomicAdd(&cnt[v.w], 1);
        }
    } else if (b < NBF + 3125) {
        int idx = (b - NBF) * 256 + tid;
        if (idx >= NN * 4) return;
        int n = idx >> 2, q = idx & 3;
        float4 v;
        if (n < NU) v = ((const float4*)uemb)[(size_t)n * 4 + q];
        else        v = ((const float4*)iemb)[(size_t)(n - NU) * 4 + q];
        f16x4 h;
        h[0] = (_Float16)v.x; h[1] = (_Float16)v.y;
        h[2] = (_Float16)v.z; h[3] = (_Float16)v.w;
        *(f16x4*)(ego16 + (size_t)n * 32 + q * 4) = h;
        ((float4*)outp)[(size_t)n * 32 + q] = v;
    } else {
        int i = (b - (NBF + 3125)) * 256 + tid;  // 0..49151
        int side = (i >= 24576);
        int ii = i - side * 24576;
        const float* W1 = side ? ieW1 : ueW1;
        int j   = ii & 7;
        int ln  = (ii >> 3) & 63;
        int kbH = ii >> 9;
        int kb  = kbH >> 1, H = kbH & 1;
        int k   = kb * 32 + (ln >> 4) * 8 + j;
        int c   = H * 16 + (ln & 15);
        w1p[i] = (_Float16)W1[k * 32 + c];
    }
}

// ---------------------------------------------------------------------------
// scan / offsets
// ---------------------------------------------------------------------------
__global__ __launch_bounds__(256) void scan_blk_kernel(const int* __restrict__ cnt,
                                                       int* __restrict__ rp,
                                                       int* __restrict__ bsum)
{
    __shared__ int ts[256];
    const int tid = threadIdx.x;
    const int base = blockIdx.x * 1024 + tid * 4;
    int v0 = (base + 0 < NN) ? cnt[base + 0] : 0;
    int v1 = (base + 1 < NN) ? cnt[base + 1] : 0;
    int v2 = (base + 2 < NN) ? cnt[base + 2] : 0;
    int v3 = (base + 3 < NN) ? cnt[base + 3] : 0;
    int s = v0 + v1 + v2 + v3;
    ts[tid] = s;
    __syncthreads();
    for (int off = 1; off < 256; off <<= 1) {
        int t = (tid >= off) ? ts[tid - off] : 0;
        __syncthreads();
        ts[tid] += t;
        __syncthreads();
    }
    int excl = ts[tid] - s;
    if (base + 0 < NN) rp[base + 0] = excl;
    if (base + 1 < NN) rp[base + 1] = excl + v0;
    if (base + 2 < NN) rp[base + 2] = excl + v0 + v1;
    if (base + 3 < NN) rp[base + 3] = excl + v0 + v1 + v2;
    if (tid == 255) bsum[blockIdx.x] = ts[255];
}

__global__ __launch_bounds__(256) void scan_bsum_kernel(int* __restrict__ bsum, int nblk)
{
    __shared__ int ts[256];
    const int tid = threadIdx.x;
    int v = (tid < nblk) ? bsum[tid] : 0;
    ts[tid] = v;
    __syncthreads();
    for (int off = 1; off < 256; off <<= 1) {
        int t = (tid >= off) ? ts[tid - off] : 0;
        __syncthreads();
        ts[tid] += t;
        __syncthreads();
    }
    if (tid < nblk) bsum[tid] = ts[tid] - v;
}

__global__ __launch_bounds__(256) void add_off_kernel(int* __restrict__ rp,
                                                      const int* __restrict__ bsum,
                                                      int* __restrict__ cur)
{
    int i = blockIdx.x * 256 + threadIdx.x;
    if (i < NN) {
        int v = rp[i] + bsum[i >> 10];
        rp[i] = v;
        cur[i] = v;
    }
    if (i == 0) rp[NN] = NE;
}

// ---------------------------------------------------------------------------
// Merged MLP + fill: blocks [0,1024) run the MFMA MLP (v4 body); blocks
// [1024,1024+NBF) run single-pass CSR fill, trailing the mlp blocks so they
// backfill retiring CUs. rec.x = col | ((row&63)<<18)
// ---------------------------------------------------------------------------
__global__ __launch_bounds__(256, 4) void mlp_fill_kernel(
    const float* __restrict__ Xu, const float* __restrict__ Xi,
    const _Float16* __restrict__ w1pack,
    const float* __restrict__ ueW2, const float* __restrict__ ieW2,
    _Float16* __restrict__ ego16,
    float* __restrict__ outp,
    const int* __restrict__ erow, const int* __restrict__ ecol,
    const float* __restrict__ eval,
    int* __restrict__ cur, uint2* __restrict__ recs)
{
    __shared__ float buf[2][4096];
    __shared__ float part[3][512];
    __shared__ _Float16 hbuf[640];

    const int tid = threadIdx.x;

    if (blockIdx.x >= 1024) {
        // ---------------- fill path (single pass) ----------------
        const int b = blockIdx.x - 1024;
        const int4*   e4 = (const int4*)erow;
        const int4*   c4 = (const int4*)ecol;
        const float4* f4 = (const float4*)eval;
        for (int c = b * 256 + tid; c < NE / 4; c += NBF * 256) {
            int4 v   = e4[c];
            int4 cc  = c4[c];
            float4 vv = f4[c];
            int p0 = atomicAdd(&cur[v.x], 1);
            recs[p0] = make_uint2((unsigned)cc.x | ((unsigned)(v.x & 63) << 18),
                                  __float_as_uint(vv.x));
            int p1 = atomicAdd(&cur[v.y], 1);
            recs[p1] = make_uint2((unsigned)cc.y | ((unsigned)(v.y & 63) << 18),
                                  __float_as_uint(vv.y));
            int p2 = atomicAdd(&cur[v.z], 1);
            recs[p2] = make_uint2((unsigned)cc.z | ((unsigned)(v.z & 63) << 18),
                                  __float_as_uint(vv.z));
            int p3 = atomicAdd(&cur[v.w], 1);
            recs[p3] = make_uint2((unsigned)cc.w | ((unsigned)(v.w & 63) << 18),
                                  __float_as_uint(vv.w));
        }
        return;
    }

    // ---------------- mlp path (v4 body) ----------------
    const int lane  = tid & 63;
    const int wv    = tid >> 6;
    const int row16 = lane & 15;
    const int cg    = lane >> 4;
    const int rx7   = row16 & 7;

    f16x8 bw2u, bw2i;
    #pragma unroll
    for (int j = 0; j < 8; ++j) {
        bw2u[j] = (_Float16)ueW2[((lane >> 4) * 8 + j) * 16 + (lane & 15)];
        bw2i[j] = (_Float16)ieW2[((lane >> 4) * 8 + j) * 16 + (lane & 15)];
    }

    const int tA = (int)(((long)blockIdx.x * 12500) >> 10);
    const int tB = (int)(((long)(blockIdx.x + 1) * 12500) >> 10);

    for (int t = tA; t < tB; ++t) {
        const bool isU = t < 6250;
        const int tile = isU ? t : t - 6250;
        const float* xt = (isU ? Xu : Xi) + (size_t)tile * 16 * TXT;
        const _Float16* w1p = w1pack + (isU ? 0 : 24576);

#define STAGE(bb, cc) do {                                                      \
            _Pragma("unroll")                                                   \
            for (int i_ = 0; i_ < 4; ++i_) {                                    \
                const int r_ = wv * 4 + i_;                                     \
                const float* g_ = xt + (size_t)r_ * TXT + (cc) * 256            \
                                  + ((lane ^ (r_ & 7)) << 2);                   \
                __builtin_amdgcn_global_load_lds((guint*)g_,                    \
                    (luint*)&buf[bb][r_ * 256], 16, 0, 0);                      \
            }                                                                   \
        } while (0)

#define MCHUNK(bb, cc) do {                                                     \
            _Pragma("unroll")                                                   \
            for (int kl2 = 0; kl2 < 2; ++kl2) {                                 \
                const int kbl = wv * 2 + kl2;                                   \
                const int kb  = (cc) * 8 + kbl;                                 \
                f16x8 b0 = *(const f16x8*)&w1p[(kb * 2 + 0) * 512 + lane * 8];  \
                f16x8 b1 = *(const f16x8*)&w1p[(kb * 2 + 1) * 512 + lane * 8];  \
                const int u0 = kbl * 8 + cg * 2;                                \
                f32x4 xa = *(const f32x4*)&buf[bb][row16 * 256 + ((u0 ^ rx7) << 2)]; \
                f32x4 xb = *(const f32x4*)&buf[bb][row16 * 256 + (((u0 + 1) ^ rx7) << 2)]; \
                f16x8 a;                                                        \
                a[0] = (_Float16)xa[0]; a[1] = (_Float16)xa[1];                 \
                a[2] = (_Float16)xa[2]; a[3] = (_Float16)xa[3];                 \
                a[4] = (_Float16)xb[0]; a[5] = (_Float16)xb[1];                 \
                a[6] = (_Float16)xb[2]; a[7] = (_Float16)xb[3];                 \
                c0 = __builtin_amdgcn_mfma_f32_16x16x32_f16(a, b0, c0, 0, 0, 0); \
                c1 = __builtin_amdgcn_mfma_f32_16x16x32_f16(a, b1, c1, 0, 0, 0); \
            }                                                                   \
        } while (0)

        f32x4 c0 = {0.f, 0.f, 0.f, 0.f};
        f32x4 c1 = {0.f, 0.f, 0.f, 0.f};

        STAGE(0, 0);
        STAGE(1, 1);
        WAIT_VM(4);
        BARRIER;
        MCHUNK(0, 0);
        WAIT_LGKM0;
        BARRIER;
        STAGE(0, 2);
        WAIT_VM(4);
        BARRIER;
        MCHUNK(1, 1);
        WAIT_LGKM0;
        WAIT_VM(0);
        BARRIER;
        MCHUNK(0, 2);
        WAIT_LGKM0;

        if (wv > 0) {
            *(f32x4*)&part[wv - 1][lane * 8]     = c0;
            *(f32x4*)&part[wv - 1][lane * 8 + 4] = c1;
            WAIT_LGKM0;
        }
        BARRIER;

        if (wv == 0) {
            #pragma unroll
            for (int p = 0; p < 3; ++p) {
                f32x4 pa = *(const f32x4*)&part[p][lane * 8];
                f32x4 pb = *(const f32x4*)&part[p][lane * 8 + 4];
                c0 += pa; c1 += pb;
            }
            #pragma unroll
            for (int j = 0; j < 4; ++j) {
                int r = cg * 4 + j;
                hbuf[r * 40 + row16]      = (_Float16)fmaxf(c0[j], 0.f);
                hbuf[r * 40 + row16 + 16] = (_Float16)fmaxf(c1[j], 0.f);
            }
            const _Float16* ap = &hbuf[row16 * 40 + cg * 8];
            f16x4 lo = *(const f16x4*)ap;
            f16x4 hi = *(const f16x4*)(ap + 4);
            f16x8 a2;
            a2[0] = lo[0]; a2[1] = lo[1]; a2[2] = lo[2]; a2[3] = lo[3];
            a2[4] = hi[0]; a2[5] = hi[1]; a2[6] = hi[2]; a2[7] = hi[3];

            f32x4 c2 = {0.f, 0.f, 0.f, 0.f};
            f16x8 bw2 = isU ? bw2u : bw2i;
            c2 = __builtin_amdgcn_mfma_f32_16x16x32_f16(a2, bw2, c2, 0, 0, 0);

            const int rbase = (isU ? 0 : NU) + tile * 16 + cg * 4;
            #pragma unroll
            for (int j = 0; j < 4; ++j) {
                float v = c2[j];
                ego16[(size_t)(rbase + j) * 32  + 16 + row16] = (_Float16)v;
                outp [(size_t)(rbase + j) * 128 + 16 + row16] = v;
            }
        }
#undef STAGE
#undef MCHUNK
    }
}

// ---------------------------------------------------------------------------
// Pull+update v2 (proven best): 32 slots x 8 dim-lanes, contiguous slot
// spans, register run-accumulation, sparse LDS-atomic flush, chunk-8 gather
// ILP, no mid-phase barriers; fused 2x32x32 update + norm.
// ---------------------------------------------------------------------------
__global__ __launch_bounds__(256) void pull_update_v2(
    const int* __restrict__ rp, const uint2* __restrict__ recs,
    const _Float16* __restrict__ egoIn, _Float16* __restrict__ egoOut,
    float* __restrict__ outp,
    const float* __restrict__ gcW, const float* __restrict__ gcb,
    const float* __restrict__ biW, const float* __restrict__ bib, int l)
{
    __shared__ float acc[64][33];
    __shared__ float Wg[32][36];
    __shared__ float Wb[32][36];
    __shared__ float bgs[32], bbs[32];

    const int tid = threadIdx.x;
    for (int i = tid; i < 64 * 33; i += 256) ((float*)acc)[i] = 0.f;
    for (int i = tid; i < 1024; i += 256) {
        Wg[i >> 5][i & 31] = gcW[l * 1024 + i];
        Wb[i >> 5][i & 31] = biW[l * 1024 + i];
    }
    if (tid < 32) { bgs[tid] = gcb[l * 32 + tid]; bbs[tid] = bib[l * 32 + tid]; }

    const int r0 = blockIdx.x * 64;
    const int eBeg = rp[r0], eEnd = rp[r0 + 64];
    __syncthreads();

    const int cnt = eEnd - eBeg;
    const int s   = tid >> 3;       // slot 0..31
    const int q   = tid & 7;        // dim quad 0..7
    const int L   = (cnt + 31) >> 5;
    const int e0  = eBeg + s * L;
    const int e1  = min(e0 + L, eEnd);

    float4 a4 = make_float4(0.f, 0.f, 0.f, 0.f);
    int curRl = -1;

    auto PROC = [&](uint2 rr, f16x4 vv) {
        int rl = rr.x >> 18;
        float a = __uint_as_float(rr.y);
        if (rl != curRl) {
            if (curRl >= 0) {
                atomicAdd(&acc[curRl][q * 4 + 0], a4.x);
                atomicAdd(&acc[curRl][q * 4 + 1], a4.y);
                atomicAdd(&acc[curRl][q * 4 + 2], a4.z);
                atomicAdd(&acc[curRl][q * 4 + 3], a4.w);
            }
            a4 = make_float4(0.f, 0.f, 0.f, 0.f);
            curRl = rl;
        }
        a4.x += a * (float)vv[0];
        a4.y += a * (float)vv[1];
        a4.z += a * (float)vv[2];
        a4.w += a * (float)vv[3];
    };

    int e = e0;
    for (; e + 8 <= e1; e += 8) {
        uint2 r0r = recs[e],     r1r = recs[e + 1];
        uint2 r2r = recs[e + 2], r3r = recs[e + 3];
        uint2 r4r = recs[e + 4], r5r = recs[e + 5];
        uint2 r6r = recs[e + 6], r7r = recs[e + 7];
        f16x4 v0 = *(const f16x4*)(egoIn + (size_t)(r0r.x & 0x3FFFF) * 32 + q * 4);
        f16x4 v1 = *(const f16x4*)(egoIn + (size_t)(r1r.x & 0x3FFFF) * 32 + q * 4);
        f16x4 v2 = *(const f16x4*)(egoIn + (size_t)(r2r.x & 0x3FFFF) * 32 + q * 4);
        f16x4 v3 = *(const f16x4*)(egoIn + (size_t)(r3r.x & 0x3FFFF) * 32 + q * 4);
        f16x4 v4 = *(const f16x4*)(egoIn + (size_t)(r4r.x & 0x3FFFF) * 32 + q * 4);
        f16x4 v5 = *(const f16x4*)(egoIn + (size_t)(r5r.x & 0x3FFFF) * 32 + q * 4);
        f16x4 v6 = *(const f16x4*)(egoIn + (size_t)(r6r.x & 0x3FFFF) * 32 + q * 4);
        f16x4 v7 = *(const f16x4*)(egoIn + (size_t)(r7r.x & 0x3FFFF) * 32 + q * 4);
        PROC(r0r, v0); PROC(r1r, v1); PROC(r2r, v2); PROC(r3r, v3);
        PROC(r4r, v4); PROC(r5r, v5); PROC(r6r, v6); PROC(r7r, v7);
    }
    for (; e < e1; ++e) {
        uint2 rr = recs[e];
        f16x4 vv = *(const f16x4*)(egoIn + (size_t)(rr.x & 0x3FFFF) * 32 + q * 4);
        PROC(rr, vv);
    }
    if (curRl >= 0) {
        atomicAdd(&acc[curRl][q * 4 + 0], a4.x);
        atomicAdd(&acc[curRl][q * 4 + 1], a4.y);
        atomicAdd(&acc[curRl][q * 4 + 2], a4.z);
        atomicAdd(&acc[curRl][q * 4 + 3], a4.w);
    }
    __syncthreads();

    // ---- update phase: 4 threads per row, 8 output dims each ----
    const int r    = tid >> 2;
    const int c    = tid & 3;
    const int node = r0 + r;
    const int j0   = c * 8;

    const _Float16* er = egoIn + (size_t)node * 32;
    f16x8 ev0 = *(const f16x8*)er;
    f16x8 ev1 = *(const f16x8*)(er + 8);
    f16x8 ev2 = *(const f16x8*)(er + 16);
    f16x8 ev3 = *(const f16x8*)(er + 24);

    float A[8], B[8];
    #pragma unroll
    for (int jj = 0; jj < 8; ++jj) { A[jj] = bgs[j0 + jj]; B[jj] = bbs[j0 + jj]; }

    #pragma unroll
    for (int kq = 0; kq < 4; ++kq) {
        #pragma unroll
        for (int kk = 0; kk < 8; ++kk) {
            const int k = kq * 8 + kk;
            float sk = acc[r][k];
            float evk = (kq == 0) ? (float)ev0[kk] : (kq == 1) ? (float)ev1[kk]
                      : (kq == 2) ? (float)ev2[kk] : (float)ev3[kk];
            float ek = sk * evk;
            f32x4 g0 = *(const f32x4*)&Wg[k][j0];
            f32x4 g1 = *(const f32x4*)&Wg[k][j0 + 4];
            f32x4 b0 = *(const f32x4*)&Wb[k][j0];
            f32x4 b1 = *(const f32x4*)&Wb[k][j0 + 4];
            A[0] += sk * g0[0]; A[1] += sk * g0[1]; A[2] += sk * g0[2]; A[3] += sk * g0[3];
            A[4] += sk * g1[0]; A[5] += sk * g1[1]; A[6] += sk * g1[2]; A[7] += sk * g1[3];
            B[0] += ek * b0[0]; B[1] += ek * b0[1]; B[2] += ek * b0[2]; B[3] += ek * b0[3];
            B[4] += ek * b1[0]; B[5] += ek * b1[1]; B[6] += ek * b1[2]; B[7] += ek * b1[3];
        }
    }

    float v[8];
    float ss = 0.f;
    #pragma unroll
    for (int jj = 0; jj < 8; ++jj) {
        float x = lrelu(A[jj]) + lrelu(B[jj]);
        v[jj] = x;
        ss += x * x;
    }
    ss += __shfl_xor(ss, 1, 64);
    ss += __shfl_xor(ss, 2, 64);
    float inv = 1.0f / fmaxf(sqrtf(ss), 1e-12f);

    f16x8 h;
    #pragma unroll
    for (int jj = 0; jj < 8; ++jj) h[jj] = (_Float16)v[jj];
    *(f16x8*)(egoOut + (size_t)node * 32 + j0) = h;

    float* op = outp + (size_t)node * 128 + (size_t)(l + 1) * 32 + j0;
    float4 o0 = make_float4(v[0] * inv, v[1] * inv, v[2] * inv, v[3] * inv);
    float4 o1 = make_float4(v[4] * inv, v[5] * inv, v[6] * inv, v[7] * inv);
    *(float4*)op       = o0;
    *(float4*)(op + 4) = o1;
}

// ---------------------------------------------------------------------------
extern "C" void kernel_launch(void* const* d_in, const int* in_sizes, int n_in,
                              void* d_out, int out_size, void* d_ws, size_t ws_size,
                              hipStream_t stream)
{
    const int*   erow = (const int*)d_in[0];
    const int*   ecol = (const int*)d_in[1];
    const float* evalp = (const float*)d_in[2];
    const float* une  = (const float*)d_in[3];
    const float* se   = (const float*)d_in[4];
    const float* uemb = (const float*)d_in[5];
    const float* iemb = (const float*)d_in[6];
    const float* ueW1 = (const float*)d_in[7];
    const float* ueW2 = (const float*)d_in[8];
    const float* ieW1 = (const float*)d_in[9];
    const float* ieW2 = (const float*)d_in[10];
    const float* gcW  = (const float*)d_in[11];
    const float* gcb  = (const float*)d_in[12];
    const float* biW  = (const float*)d_in[13];
    const float* bib  = (const float*)d_in[14];
    float* outp = (float*)d_out;

    _Float16* egoA16 = (_Float16*)d_ws;                 // NN*32 f16 = 12.8 MB
    _Float16* egoB16 = egoA16 + (size_t)NN * 32;        // 12.8 MB
    uint2* recs = (uint2*)(egoB16 + (size_t)NN * 32);   // NE uint2 = 25.6 MB
    int*   cnt  = (int*)(recs + (size_t)NE);            // NN
    int*   rp   = cnt + NN;                             // NN+1
    int*   cur  = rp + NN + 1;                          // NN
    int*   bsum = cur + NN;                             // 256
    _Float16* w1pack = (_Float16*)(bsum + 256);         // 2*24576 f16 = 96 KB

    const size_t need = (size_t)((char*)(w1pack + 49152) - (char*)d_ws);
    if (ws_size < need) return;

    hipMemsetAsync(cnt, 0, (size_t)NN * sizeof(int), stream);
    prep_kernel<<<NBF + 3125 + 192, 256, 0, stream>>>(erow, uemb, iemb, ueW1, ieW1,
                                                      cnt, egoA16, outp, w1pack);

    const int NBLK = (NN + 1023) / 1024;  // 196
    scan_blk_kernel<<<NBLK, 256, 0, stream>>>(cnt, rp, bsum);
    scan_bsum_kernel<<<1, 256, 0, stream>>>(bsum, NBLK);
    add_off_kernel<<<(NN + 255) / 256, 256, 0, stream>>>(rp, bsum, cur);

    // mlp and fill are independent: co-run them in one launch (mlp first).
    mlp_fill_kernel<<<1024 + NBF, 256, 0, stream>>>(
        une, se, w1pack, ueW2, ieW2, egoA16, outp,
        erow, ecol, evalp, cur, recs);

    const _Float16* egoIn = egoA16;
    _Float16* egoOut = egoB16;
    for (int l = 0; l < 3; ++l) {
        pull_update_v2<<<NN / 64, 256, 0, stream>>>(rp, recs, egoIn, egoOut, outp,
                                                    gcW, gcb, biW, bib, l);
        const _Float16* t = egoOut; egoOut = (_Float16*)egoIn; egoIn = t;
    }
}

// Round 18
// 635.487 us; speedup vs baseline: 1.0993x; 1.0496x over previous
//
#include <hip/hip_runtime.h>
#include <cstdint>

#define NU 100000
#define NI 100000
#define NN 200000
#define NE 3200000
#define TXT 768
#define NBF 640        // blocks for non-ranged count/fill passes

typedef _Float16 f16x8 __attribute__((ext_vector_type(8)));
typedef _Float16 f16x4 __attribute__((ext_vector_type(4)));
typedef float    f32x4 __attribute__((ext_vector_type(4)));

typedef __attribute__((address_space(1))) const unsigned int guint;
typedef __attribute__((address_space(3))) unsigned int luint;

__device__ __forceinline__ float lrelu(float x) { return x >= 0.f ? x : 0.01f * x; }

#define MEMFENCE asm volatile("" ::: "memory")
#define WAIT_VM(N)  asm volatile("s_waitcnt vmcnt(" #N ")" ::: "memory")
#define WAIT_LGKM0  asm volatile("s_waitcnt lgkmcnt(0)" ::: "memory")
#define BARRIER     do { __builtin_amdgcn_s_barrier(); MEMFENCE; } while (0)

// ---------------------------------------------------------------------------
// prep: [0,640) count (single pass) | [640,3765) copy_emb | [3765,3957) pack_w1
// ---------------------------------------------------------------------------
__global__ __launch_bounds__(256) void prep_kernel(
    const int* __restrict__ erow,
    const float* __restrict__ uemb, const float* __restrict__ iemb,
    const float* __restrict__ ueW1, const float* __restrict__ ieW1,
    int* __restrict__ cnt,
    _Float16* __restrict__ ego16, float* __restrict__ outp,
    _Float16* __restrict__ w1p)
{
    const int b = blockIdx.x;
    const int tid = threadIdx.x;

    if (b < NBF) {
        const int4* e4 = (const int4*)erow;
        for (int c = b * 256 + tid; c < NE / 4; c += NBF * 256) {
            int4 v = e4[c];
            atomicAdd(&cnt[v.x], 1);
            atomicAdd(&cnt[v.y], 1);
            atomicAdd(&cnt[v.z], 1);
            atomicAdd(&cnt[v.w], 1);
        }
    } else if (b < NBF + 3125) {
        int idx = (b - NBF) * 256 + tid;
        if (idx >= NN * 4) return;
        int n = idx >> 2, q = idx & 3;
        float4 v;
        if (n < NU) v = ((const float4*)uemb)[(size_t)n * 4 + q];
        else        v = ((const float4*)iemb)[(size_t)(n - NU) * 4 + q];
        f16x4 h;
        h[0] = (_Float16)v.x; h[1] = (_Float16)v.y;
        h[2] = (_Float16)v.z; h[3] = (_Float16)v.w;
        *(f16x4*)(ego16 + (size_t)n * 32 + q * 4) = h;
        ((float4*)outp)[(size_t)n * 32 + q] = v;
    } else {
        int i = (b - (NBF + 3125)) * 256 + tid;  // 0..49151
        int side = (i >= 24576);
        int ii = i - side * 24576;
        const float* W1 = side ? ieW1 : ueW1;
        int j   = ii & 7;
        int ln  = (ii >> 3) & 63;
        int kbH = ii >> 9;
        int kb  = kbH >> 1, H = kbH & 1;
        int k   = kb * 32 + (ln >> 4) * 8 + j;
        int c   = H * 16 + (ln & 15);
        w1p[i] = (_Float16)W1[k * 32 + c];
    }
}

// ---------------------------------------------------------------------------
// scan / offsets
// ---------------------------------------------------------------------------
__global__ __launch_bounds__(256) void scan_blk_kernel(const int* __restrict__ cnt,
                                                       int* __restrict__ rp,
                                                       int* __restrict__ bsum)
{
    __shared__ int ts[256];
    const int tid = threadIdx.x;
    const int base = blockIdx.x * 1024 + tid * 4;
    int v0 = (base + 0 < NN) ? cnt[base + 0] : 0;
    int v1 = (base + 1 < NN) ? cnt[base + 1] : 0;
    int v2 = (base + 2 < NN) ? cnt[base + 2] : 0;
    int v3 = (base + 3 < NN) ? cnt[base + 3] : 0;
    int s = v0 + v1 + v2 + v3;
    ts[tid] = s;
    __syncthreads();
    for (int off = 1; off < 256; off <<= 1) {
        int t = (tid >= off) ? ts[tid - off] : 0;
        __syncthreads();
        ts[tid] += t;
        __syncthreads();
    }
    int excl = ts[tid] - s;
    if (base + 0 < NN) rp[base + 0] = excl;
    if (base + 1 < NN) rp[base + 1] = excl + v0;
    if (base + 2 < NN) rp[base + 2] = excl + v0 + v1;
    if (base + 3 < NN) rp[base + 3] = excl + v0 + v1 + v2;
    if (tid == 255) bsum[blockIdx.x] = ts[255];
}

__global__ __launch_bounds__(256) void scan_bsum_kernel(int* __restrict__ bsum, int nblk)
{
    __shared__ int ts[256];
    const int tid = threadIdx.x;
    int v = (tid < nblk) ? bsum[tid] : 0;
    ts[tid] = v;
    __syncthreads();
    for (int off = 1; off < 256; off <<= 1) {
        int t = (tid >= off) ? ts[tid - off] : 0;
        __syncthreads();
        ts[tid] += t;
        __syncthreads();
    }
    if (tid < nblk) bsum[tid] = ts[tid] - v;
}

__global__ __launch_bounds__(256) void add_off_kernel(int* __restrict__ rp,
                                                      const int* __restrict__ bsum,
                                                      int* __restrict__ cur)
{
    int i = blockIdx.x * 256 + threadIdx.x;
    if (i < NN) {
        int v = rp[i] + bsum[i >> 10];
        rp[i] = v;
        cur[i] = v;
    }
    if (i == 0) rp[NN] = NE;
}

// ---------------------------------------------------------------------------
// Merged MLP + fill. Blocks [0,1024) = MFMA MLP, v5: 8-KB chunks (16 rows x
// 128 f32), 6 chunks/tile, 1 K-block/wave/chunk, LDS 23.8 KB -> 6 blocks/CU
// (24 waves, vs v4's 16). Staging: 2 x 1-KB contiguous global_load_lds per
// wave per chunk (2 rows each, lane>>5 = row, XOR swizzle unit^(r&7)).
// Blocks [1024,1024+NBF) = single-pass CSR fill (trailing backfill).
// rec.x = col | ((row&63)<<18)
// ---------------------------------------------------------------------------
__global__ __launch_bounds__(256, 6) void mlp_fill_kernel(
    const float* __restrict__ Xu, const float* __restrict__ Xi,
    const _Float16* __restrict__ w1pack,
    const float* __restrict__ ueW2, const float* __restrict__ ieW2,
    _Float16* __restrict__ ego16,
    float* __restrict__ outp,
    const int* __restrict__ erow, const int* __restrict__ ecol,
    const float* __restrict__ eval,
    int* __restrict__ cur, uint2* __restrict__ recs)
{
    __shared__ float buf[2][2048];     // 2 x 8 KB chunk: row r at [r*128, +128)
    __shared__ float part[3][512];     // partial C from waves 1..3
    __shared__ _Float16 hbuf[640];     // wave-0 epilogue h (16 x 40)

    const int tid = threadIdx.x;

    if (blockIdx.x >= 1024) {
        // ---------------- fill path (single pass) ----------------
        const int b = blockIdx.x - 1024;
        const int4*   e4 = (const int4*)erow;
        const int4*   c4 = (const int4*)ecol;
        const float4* f4 = (const float4*)eval;
        for (int c = b * 256 + tid; c < NE / 4; c += NBF * 256) {
            int4 v   = e4[c];
            int4 cc  = c4[c];
            float4 vv = f4[c];
            int p0 = atomicAdd(&cur[v.x], 1);
            recs[p0] = make_uint2((unsigned)cc.x | ((unsigned)(v.x & 63) << 18),
                                  __float_as_uint(vv.x));
            int p1 = atomicAdd(&cur[v.y], 1);
            recs[p1] = make_uint2((unsigned)cc.y | ((unsigned)(v.y & 63) << 18),
                                  __float_as_uint(vv.y));
            int p2 = atomicAdd(&cur[v.z], 1);
            recs[p2] = make_uint2((unsigned)cc.z | ((unsigned)(v.z & 63) << 18),
                                  __float_as_uint(vv.z));
            int p3 = atomicAdd(&cur[v.w], 1);
            recs[p3] = make_uint2((unsigned)cc.w | ((unsigned)(v.w & 63) << 18),
                                  __float_as_uint(vv.w));
        }
        return;
    }

    // ---------------- mlp path (v5) ----------------
    const int lane  = tid & 63;
    const int wv    = tid >> 6;
    const int row16 = lane & 15;
    const int cg    = lane >> 4;
    const int rx7   = row16 & 7;

    f16x8 bw2u, bw2i;
    #pragma unroll
    for (int j = 0; j < 8; ++j) {
        bw2u[j] = (_Float16)ueW2[((lane >> 4) * 8 + j) * 16 + (lane & 15)];
        bw2i[j] = (_Float16)ieW2[((lane >> 4) * 8 + j) * 16 + (lane & 15)];
    }

    const int tA = (int)(((long)blockIdx.x * 12500) >> 10);
    const int tB = (int)(((long)(blockIdx.x + 1) * 12500) >> 10);

    for (int t = tA; t < tB; ++t) {
        const bool isU = t < 6250;
        const int tile = isU ? t : t - 6250;
        const float* xt = (isU ? Xu : Xi) + (size_t)tile * 16 * TXT;
        const _Float16* w1p = w1pack + (isU ? 0 : 24576);

        // stage chunk cc (16 rows x 128 f32) into buf bb; wave stages its 4
        // rows with 2 instructions (2 rows / 1 KB each, lane>>5 selects row).
#define STAGE(bb, cc) do {                                                      \
            _Pragma("unroll")                                                   \
            for (int i_ = 0; i_ < 2; ++i_) {                                    \
                const int rb_ = wv * 4 + i_ * 2;                                \
                const int r_  = rb_ + (lane >> 5);                              \
                const float* g_ = xt + (size_t)r_ * TXT + (cc) * 128            \
                                  + (((lane & 31) ^ (r_ & 7)) << 2);            \
                __builtin_amdgcn_global_load_lds((guint*)g_,                    \
                    (luint*)&buf[bb][rb_ * 128], 16, 0, 0);                     \
            }                                                                   \
        } while (0)

        // MFMA over this wave's single K-block (kb = cc*4 + wv) of chunk cc
#define MCHUNK(bb, cc) do {                                                     \
            const int kb = (cc) * 4 + wv;                                       \
            f16x8 b0 = *(const f16x8*)&w1p[(kb * 2 + 0) * 512 + lane * 8];      \
            f16x8 b1 = *(const f16x8*)&w1p[(kb * 2 + 1) * 512 + lane * 8];      \
            const int u0 = wv * 8 + cg * 2;                                     \
            f32x4 xa = *(const f32x4*)&buf[bb][row16 * 128 + ((u0 ^ rx7) << 2)]; \
            f32x4 xb = *(const f32x4*)&buf[bb][row16 * 128 + (((u0 + 1) ^ rx7) << 2)]; \
            f16x8 a;                                                            \
            a[0] = (_Float16)xa[0]; a[1] = (_Float16)xa[1];                     \
            a[2] = (_Float16)xa[2]; a[3] = (_Float16)xa[3];                     \
            a[4] = (_Float16)xb[0]; a[5] = (_Float16)xb[1];                     \
            a[6] = (_Float16)xb[2]; a[7] = (_Float16)xb[3];                     \
            c0 = __builtin_amdgcn_mfma_f32_16x16x32_f16(a, b0, c0, 0, 0, 0);    \
            c1 = __builtin_amdgcn_mfma_f32_16x16x32_f16(a, b1, c1, 0, 0, 0);    \
        } while (0)

        f32x4 c0 = {0.f, 0.f, 0.f, 0.f};
        f32x4 c1 = {0.f, 0.f, 0.f, 0.f};

        // u0 within each K-block row-slice must use kbl=wv units offset:
        // chunk row = 128 f32 = 32 units; K-block wv occupies units wv*8..+8.

        STAGE(0, 0);
        STAGE(1, 1);
        WAIT_VM(2);  BARRIER;            // chunk0 landed
        MCHUNK(0, 0); WAIT_LGKM0; BARRIER;
        STAGE(0, 2);
        WAIT_VM(2);  BARRIER;            // chunk1 landed (chunk2 in flight)
        MCHUNK(1, 1); WAIT_LGKM0; BARRIER;
        STAGE(1, 3);
        WAIT_VM(2);  BARRIER;            // chunk2 landed
        MCHUNK(0, 2); WAIT_LGKM0; BARRIER;
        STAGE(0, 4);
        WAIT_VM(2);  BARRIER;            // chunk3 landed
        MCHUNK(1, 3); WAIT_LGKM0; BARRIER;
        STAGE(1, 5);
        WAIT_VM(2);  BARRIER;            // chunk4 landed
        MCHUNK(0, 4); WAIT_LGKM0;
        WAIT_VM(0);  BARRIER;            // chunk5 landed
        MCHUNK(1, 5); WAIT_LGKM0;

        // ---- reduce partials + epilogue (wave 0) ----
        if (wv > 0) {
            *(f32x4*)&part[wv - 1][lane * 8]     = c0;
            *(f32x4*)&part[wv - 1][lane * 8 + 4] = c1;
            WAIT_LGKM0;
        }
        BARRIER;

        if (wv == 0) {
            #pragma unroll
            for (int p = 0; p < 3; ++p) {
                f32x4 pa = *(const f32x4*)&part[p][lane * 8];
                f32x4 pb = *(const f32x4*)&part[p][lane * 8 + 4];
                c0 += pa; c1 += pb;
            }
            #pragma unroll
            for (int j = 0; j < 4; ++j) {
                int r = cg * 4 + j;
                hbuf[r * 40 + row16]      = (_Float16)fmaxf(c0[j], 0.f);
                hbuf[r * 40 + row16 + 16] = (_Float16)fmaxf(c1[j], 0.f);
            }
            const _Float16* ap = &hbuf[row16 * 40 + cg * 8];
            f16x4 lo = *(const f16x4*)ap;
            f16x4 hi = *(const f16x4*)(ap + 4);
            f16x8 a2;
            a2[0] = lo[0]; a2[1] = lo[1]; a2[2] = lo[2]; a2[3] = lo[3];
            a2[4] = hi[0]; a2[5] = hi[1]; a2[6] = hi[2]; a2[7] = hi[3];

            f32x4 c2 = {0.f, 0.f, 0.f, 0.f};
            f16x8 bw2 = isU ? bw2u : bw2i;
            c2 = __builtin_amdgcn_mfma_f32_16x16x32_f16(a2, bw2, c2, 0, 0, 0);

            const int rbase = (isU ? 0 : NU) + tile * 16 + cg * 4;
            #pragma unroll
            for (int j = 0; j < 4; ++j) {
                float v = c2[j];
                ego16[(size_t)(rbase + j) * 32  + 16 + row16] = (_Float16)v;
                outp [(size_t)(rbase + j) * 128 + 16 + row16] = v;
            }
        }
#undef STAGE
#undef MCHUNK
    }
}

// ---------------------------------------------------------------------------
// Pull+update v2 (proven best): 32 slots x 8 dim-lanes, contiguous slot
// spans, register run-accumulation, sparse LDS-atomic flush, chunk-8 gather
// ILP, no mid-phase barriers; fused 2x32x32 update + norm.
// ---------------------------------------------------------------------------
__global__ __launch_bounds__(256) void pull_update_v2(
    const int* __restrict__ rp, const uint2* __restrict__ recs,
    const _Float16* __restrict__ egoIn, _Float16* __restrict__ egoOut,
    float* __restrict__ outp,
    const float* __restrict__ gcW, const float* __restrict__ gcb,
    const float* __restrict__ biW, const float* __restrict__ bib, int l)
{
    __shared__ float acc[64][33];
    __shared__ float Wg[32][36];
    __shared__ float Wb[32][36];
    __shared__ float bgs[32], bbs[32];

    const int tid = threadIdx.x;
    for (int i = tid; i < 64 * 33; i += 256) ((float*)acc)[i] = 0.f;
    for (int i = tid; i < 1024; i += 256) {
        Wg[i >> 5][i & 31] = gcW[l * 1024 + i];
        Wb[i >> 5][i & 31] = biW[l * 1024 + i];
    }
    if (tid < 32) { bgs[tid] = gcb[l * 32 + tid]; bbs[tid] = bib[l * 32 + tid]; }

    const int r0 = blockIdx.x * 64;
    const int eBeg = rp[r0], eEnd = rp[r0 + 64];
    __syncthreads();

    const int cnt = eEnd - eBeg;
    const int s   = tid >> 3;       // slot 0..31
    const int q   = tid & 7;        // dim quad 0..7
    const int L   = (cnt + 31) >> 5;
    const int e0  = eBeg + s * L;
    const int e1  = min(e0 + L, eEnd);

    float4 a4 = make_float4(0.f, 0.f, 0.f, 0.f);
    int curRl = -1;

    auto PROC = [&](uint2 rr, f16x4 vv) {
        int rl = rr.x >> 18;
        float a = __uint_as_float(rr.y);
        if (rl != curRl) {
            if (curRl >= 0) {
                atomicAdd(&acc[curRl][q * 4 + 0], a4.x);
                atomicAdd(&acc[curRl][q * 4 + 1], a4.y);
                atomicAdd(&acc[curRl][q * 4 + 2], a4.z);
                atomicAdd(&acc[curRl][q * 4 + 3], a4.w);
            }
            a4 = make_float4(0.f, 0.f, 0.f, 0.f);
            curRl = rl;
        }
        a4.x += a * (float)vv[0];
        a4.y += a * (float)vv[1];
        a4.z += a * (float)vv[2];
        a4.w += a * (float)vv[3];
    };

    int e = e0;
    for (; e + 8 <= e1; e += 8) {
        uint2 r0r = recs[e],     r1r = recs[e + 1];
        uint2 r2r = recs[e + 2], r3r = recs[e + 3];
        uint2 r4r = recs[e + 4], r5r = recs[e + 5];
        uint2 r6r = recs[e + 6], r7r = recs[e + 7];
        f16x4 v0 = *(const f16x4*)(egoIn + (size_t)(r0r.x & 0x3FFFF) * 32 + q * 4);
        f16x4 v1 = *(const f16x4*)(egoIn + (size_t)(r1r.x & 0x3FFFF) * 32 + q * 4);
        f16x4 v2 = *(const f16x4*)(egoIn + (size_t)(r2r.x & 0x3FFFF) * 32 + q * 4);
        f16x4 v3 = *(const f16x4*)(egoIn + (size_t)(r3r.x & 0x3FFFF) * 32 + q * 4);
        f16x4 v4 = *(const f16x4*)(egoIn + (size_t)(r4r.x & 0x3FFFF) * 32 + q * 4);
        f16x4 v5 = *(const f16x4*)(egoIn + (size_t)(r5r.x & 0x3FFFF) * 32 + q * 4);
        f16x4 v6 = *(const f16x4*)(egoIn + (size_t)(r6r.x & 0x3FFFF) * 32 + q * 4);
        f16x4 v7 = *(const f16x4*)(egoIn + (size_t)(r7r.x & 0x3FFFF) * 32 + q * 4);
        PROC(r0r, v0); PROC(r1r, v1); PROC(r2r, v2); PROC(r3r, v3);
        PROC(r4r, v4); PROC(r5r, v5); PROC(r6r, v6); PROC(r7r, v7);
    }
    for (; e < e1; ++e) {
        uint2 rr = recs[e];
        f16x4 vv = *(const f16x4*)(egoIn + (size_t)(rr.x & 0x3FFFF) * 32 + q * 4);
        PROC(rr, vv);
    }
    if (curRl >= 0) {
        atomicAdd(&acc[curRl][q * 4 + 0], a4.x);
        atomicAdd(&acc[curRl][q * 4 + 1], a4.y);
        atomicAdd(&acc[curRl][q * 4 + 2], a4.z);
        atomicAdd(&acc[curRl][q * 4 + 3], a4.w);
    }
    __syncthreads();

    // ---- update phase: 4 threads per row, 8 output dims each ----
    const int r    = tid >> 2;
    const int c    = tid & 3;
    const int node = r0 + r;
    const int j0   = c * 8;

    const _Float16* er = egoIn + (size_t)node * 32;
    f16x8 ev0 = *(const f16x8*)er;
    f16x8 ev1 = *(const f16x8*)(er + 8);
    f16x8 ev2 = *(const f16x8*)(er + 16);
    f16x8 ev3 = *(const f16x8*)(er + 24);

    float A[8], B[8];
    #pragma unroll
    for (int jj = 0; jj < 8; ++jj) { A[jj] = bgs[j0 + jj]; B[jj] = bbs[j0 + jj]; }

    #pragma unroll
    for (int kq = 0; kq < 4; ++kq) {
        #pragma unroll
        for (int kk = 0; kk < 8; ++kk) {
            const int k = kq * 8 + kk;
            float sk = acc[r][k];
            float evk = (kq == 0) ? (float)ev0[kk] : (kq == 1) ? (float)ev1[kk]
                      : (kq == 2) ? (float)ev2[kk] : (float)ev3[kk];
            float ek = sk * evk;
            f32x4 g0 = *(const f32x4*)&Wg[k][j0];
            f32x4 g1 = *(const f32x4*)&Wg[k][j0 + 4];
            f32x4 b0 = *(const f32x4*)&Wb[k][j0];
            f32x4 b1 = *(const f32x4*)&Wb[k][j0 + 4];
            A[0] += sk * g0[0]; A[1] += sk * g0[1]; A[2] += sk * g0[2]; A[3] += sk * g0[3];
            A[4] += sk * g1[0]; A[5] += sk * g1[1]; A[6] += sk * g1[2]; A[7] += sk * g1[3];
            B[0] += ek * b0[0]; B[1] += ek * b0[1]; B[2] += ek * b0[2]; B[3] += ek * b0[3];
            B[4] += ek * b1[0]; B[5] += ek * b1[1]; B[6] += ek * b1[2]; B[7] += ek * b1[3];
        }
    }

    float v[8];
    float ss = 0.f;
    #pragma unroll
    for (int jj = 0; jj < 8; ++jj) {
        float x = lrelu(A[jj]) + lrelu(B[jj]);
        v[jj] = x;
        ss += x * x;
    }
    ss += __shfl_xor(ss, 1, 64);
    ss += __shfl_xor(ss, 2, 64);
    float inv = 1.0f / fmaxf(sqrtf(ss), 1e-12f);

    f16x8 h;
    #pragma unroll
    for (int jj = 0; jj < 8; ++jj) h[jj] = (_Float16)v[jj];
    *(f16x8*)(egoOut + (size_t)node * 32 + j0) = h;

    float* op = outp + (size_t)node * 128 + (size_t)(l + 1) * 32 + j0;
    float4 o0 = make_float4(v[0] * inv, v[1] * inv, v[2] * inv, v[3] * inv);
    float4 o1 = make_float4(v[4] * inv, v[5] * inv, v[6] * inv, v[7] * inv);
    *(float4*)op       = o0;
    *(float4*)(op + 4) = o1;
}

// ---------------------------------------------------------------------------
extern "C" void kernel_launch(void* const* d_in, const int* in_sizes, int n_in,
                              void* d_out, int out_size, void* d_ws, size_t ws_size,
                              hipStream_t stream)
{
    const int*   erow = (const int*)d_in[0];
    const int*   ecol = (const int*)d_in[1];
    const float* evalp = (const float*)d_in[2];
    const float* une  = (const float*)d_in[3];
    const float* se   = (const float*)d_in[4];
    const float* uemb = (const float*)d_in[5];
    const float* iemb = (const float*)d_in[6];
    const float* ueW1 = (const float*)d_in[7];
    const float* ueW2 = (const float*)d_in[8];
    const float* ieW1 = (const float*)d_in[9];
    const float* ieW2 = (const float*)d_in[10];
    const float* gcW  = (const float*)d_in[11];
    const float* gcb  = (const float*)d_in[12];
    const float* biW  = (const float*)d_in[13];
    const float* bib  = (const float*)d_in[14];
    float* outp = (float*)d_out;

    _Float16* egoA16 = (_Float16*)d_ws;                 // NN*32 f16 = 12.8 MB
    _Float16* egoB16 = egoA16 + (size_t)NN * 32;        // 12.8 MB
    uint2* recs = (uint2*)(egoB16 + (size_t)NN * 32);   // NE uint2 = 25.6 MB
    int*   cnt  = (int*)(recs + (size_t)NE);            // NN
    int*   rp   = cnt + NN;                             // NN+1
    int*   cur  = rp + NN + 1;                          // NN
    int*   bsum = cur + NN;                             // 256
    _Float16* w1pack = (_Float16*)(bsum + 256);         // 2*24576 f16 = 96 KB

    const size_t need = (size_t)((char*)(w1pack + 49152) - (char*)d_ws);
    if (ws_size < need) return;

    hipMemsetAsync(cnt, 0, (size_t)NN * sizeof(int), stream);
    prep_kernel<<<NBF + 3125 + 192, 256, 0, stream>>>(erow, uemb, iemb, ueW1, ieW1,
                                                      cnt, egoA16, outp, w1pack);

    const int NBLK = (NN + 1023) / 1024;  // 196
    scan_blk_kernel<<<NBLK, 256, 0, stream>>>(cnt, rp, bsum);
    scan_bsum_kernel<<<1, 256, 0, stream>>>(bsum, NBLK);
    add_off_kernel<<<(NN + 255) / 256, 256, 0, stream>>>(rp, bsum, cur);

    // mlp and fill are independent: co-run them in one launch (mlp first).
    mlp_fill_kernel<<<1024 + NBF, 256, 0, stream>>>(
        une, se, w1pack, ueW2, ieW2, egoA16, outp,
        erow, ecol, evalp, cur, recs);

    const _Float16* egoIn = egoA16;
    _Float16* egoOut = egoB16;
    for (int l = 0; l < 3; ++l) {
        pull_update_v2<<<NN / 64, 256, 0, stream>>>(rp, recs, egoIn, egoOut, outp,
                                                    gcW, gcb, biW, bib, l);
        const _Float16* t = egoOut; egoOut = (_Float16*)egoIn; egoIn = t;
    }
}